// Round 5
// baseline (878.537 us; speedup 1.0000x reference)
//
#include <hip/hip_runtime.h>
#include <hip/hip_bf16.h>

// ---------------------------------------------------------------------------
// KGATNE, fp32 in / fp32 out (confirmed R4: passed with absmax 4.9e-4).
// Split pipeline:
//   A pass0_l3 : pass-0 level-3 rows (3 graphs x 53760 rows), embarrassingly
//                parallel, 2-wave output split (self/neigh halves), weights in
//                VGPRs, ~2KB LDS, no barriers. -> H3 in ws (64.5 MB).
//   B sage_tree: per-(b,g) tree for levels 0..2 across passes 0..3 + fc,
//                double-buffered 19-row LDS feat, 4 barriers. -> SPEC in ws.
//   C attn_out : wave-role-split attention + select + reflect + l2norm.
// Fallback: if ws_size < 68.7 MB, monolithic R4 kernel (proven) + attn v2.
// Sizes: B=512 G=3 D=100 DIN=200 N=100000, S={3,5,7,9}
// ---------------------------------------------------------------------------

#define DEVFN __device__ __forceinline__

// ---------------------------------------------------------------------------
// Kernel A: pass-0 level-3.  row r (per g) in [0,53760): x = n2[g][r],
// children = n3[g][r*9..r*9+9).  out H3[g][r][0:50]=self, [50:100]=neigh.
// 1344 waves per g; each wave: 40 rows self-phase then 40 rows neigh-phase
// (balanced; weights loaded once per phase, 100 VGPRs).
// ---------------------------------------------------------------------------
__global__ __launch_bounds__(256, 3) void pass0_l3(
    const int* __restrict__ n2, const int* __restrict__ n3,
    const float* __restrict__ emb, const float* __restrict__ Wself,
    const float* __restrict__ bself, const float* __restrict__ Wneigh,
    const float* __restrict__ bneigh, float* __restrict__ H3) {
    const int g = blockIdx.y;
    const int wid = threadIdx.x >> 6, lane = threadIdx.x & 63;
    const int w = blockIdx.x * 4 + wid;  // 0..1343
    const int c = min(lane, 49);
    const float* embg = emb + (size_t)g * 10000000;
    const int* n2g = n2 + g * 53760;
    const int* n3g = n3 + (size_t)g * 483840;
    float* H3g = H3 + (size_t)g * 5376000;

    __shared__ __align__(16) float snb[4][104];

    float wcol[100];
    const int r0 = w * 40;

    // ---- self phase: out cols 0..49
    {
        const float* Wsb = Wself + (size_t)g * 4 * 5000;  // layer 0
#pragma unroll
        for (int d = 0; d < 100; ++d) wcol[d] = Wsb[d * 50 + c];
        const float bias = bself[g * 4 * 50 + c];
        for (int r = r0; r < r0 + 40; ++r) {
            const float* xrow = embg + (size_t)n2g[r] * 100;
            float acc = bias;
#pragma unroll
            for (int d = 0; d < 100; d += 4) {
                float4 xv = *(const float4*)(xrow + d);  // same-addr broadcast
                acc += xv.x * wcol[d] + xv.y * wcol[d + 1] + xv.z * wcol[d + 2] +
                       xv.w * wcol[d + 3];
            }
            if (lane < 50) H3g[(size_t)r * 100 + lane] = fmaxf(acc, 0.f);
        }
    }
    // ---- neigh phase: out cols 50..99
    {
        const float* Wnb = Wneigh + (size_t)g * 4 * 5000;
#pragma unroll
        for (int d = 0; d < 100; ++d) wcol[d] = Wnb[d * 50 + c];
        const float bias = bneigh[g * 4 * 50 + c];
        for (int r = r0; r < r0 + 40; ++r) {
            const int* ch = n3g + (size_t)r * 9;
            float a0 = 0.f, a1 = 0.f;
#pragma unroll
            for (int s = 0; s < 9; ++s) {
                float2 v = *(const float2*)(embg + (size_t)ch[s] * 100 + 2 * c);
                a0 += v.x;
                a1 += v.y;
            }
            if (lane < 50)
                *(float2*)&snb[wid][2 * lane] =
                    make_float2(a0 * (1.f / 9.f), a1 * (1.f / 9.f));
            // same-wave LDS write->read; compiler inserts lgkmcnt wait
            float acc = bias;
#pragma unroll
            for (int d = 0; d < 100; d += 4) {
                float4 nv = *(const float4*)&snb[wid][d];
                acc += nv.x * wcol[d] + nv.y * wcol[d + 1] + nv.z * wcol[d + 2] +
                       nv.w * wcol[d + 3];
            }
            if (lane < 50) H3g[(size_t)r * 100 + lane + 50] = fmaxf(acc, 0.f);
        }
    }
}

// ---------------------------------------------------------------------------
// Kernel B: per-(b,g) tree, levels 0..2.  wid&1 = half (0 self / 1 neigh),
// wid>>1 = row parity.  Double-buffered feat (A/B), 4 pass barriers.
// ---------------------------------------------------------------------------
__global__ __launch_bounds__(256, 3) void sage_tree(
    const int* __restrict__ nodeids, const int* __restrict__ n0,
    const int* __restrict__ n1, const int* __restrict__ n2,
    const float* __restrict__ emb, const float* __restrict__ Wself,
    const float* __restrict__ bself, const float* __restrict__ Wneigh,
    const float* __restrict__ bneigh, const float* __restrict__ Wfc,
    const float* __restrict__ bfc, const float* __restrict__ H3,
    float* __restrict__ spec) {
    const int b = blockIdx.x, g = blockIdx.y;
    const int tid = threadIdx.x, wid = tid >> 6, lane = tid & 63;
    const int half = wid & 1, rp = wid >> 1;
    const int c = min(lane, 49);

    __shared__ __align__(16) float featA[1904];
    __shared__ __align__(16) float featB[1904];
    __shared__ __align__(16) float snb[4][104];
    __shared__ int s_ids[124];

    const float* embg = emb + (size_t)g * 10000000;
    const float* H3g = H3 + (size_t)g * 5376000;

    if (tid == 0)       s_ids[0]   = nodeids[b];
    else if (tid < 4)   s_ids[tid] = n0[g * 1536  + b * 3   + (tid - 1)];
    else if (tid < 19)  s_ids[tid] = n1[g * 7680  + b * 15  + (tid - 4)];
    else if (tid < 124) s_ids[tid] = n2[g * 53760 + b * 105 + (tid - 19)];
    __syncthreads();

    float wcol[100];
    float bias;
    auto load_w = [&](int l) {
        const float* Wb = (half ? Wneigh : Wself) + (size_t)(g * 4 + l) * 5000;
#pragma unroll
        for (int d = 0; d < 100; ++d) wcol[d] = Wb[d * 50 + c];
        bias = (half ? bneigh : bself)[(g * 4 + l) * 50 + c];
    };
    auto mat_half = [&](const float* xb) -> float {  // 16B-aligned, broadcast
        float acc = bias;
#pragma unroll
        for (int d = 0; d < 100; d += 4) {
            float4 xv = *(const float4*)(xb + d);
            acc += xv.x * wcol[d] + xv.y * wcol[d + 1] + xv.z * wcol[d + 2] +
                   xv.w * wcol[d + 3];
        }
        return fmaxf(acc, 0.f);
    };
    // neigh: children rows at chb + s*100 (LDS or global), mean->snb->matmul
    auto neigh_row = [&](const float* chb, int S, float* dst) {
        float a0 = 0.f, a1 = 0.f;
        for (int s = 0; s < S; ++s) {
            float2 v = *(const float2*)(chb + s * 100 + 2 * c);
            a0 += v.x;
            a1 += v.y;
        }
        const float inv = 1.f / (float)S;
        if (lane < 50)
            *(float2*)&snb[wid][2 * lane] = make_float2(a0 * inv, a1 * inv);
        float r = mat_half(snb[wid]);
        if (lane < 50) dst[50 + lane] = r;
    };
    // neigh with per-child indirection through s_ids (pass 0 from emb)
    auto neigh_row_emb = [&](int idbase, int S, float* dst) {
        float a0 = 0.f, a1 = 0.f;
        for (int s = 0; s < S; ++s) {
            float2 v =
                *(const float2*)(embg + (size_t)s_ids[idbase + s] * 100 + 2 * c);
            a0 += v.x;
            a1 += v.y;
        }
        const float inv = 1.f / (float)S;
        if (lane < 50)
            *(float2*)&snb[wid][2 * lane] = make_float2(a0 * inv, a1 * inv);
        float r = mat_half(snb[wid]);
        if (lane < 50) dst[50 + lane] = r;
    };

    // ---- pass 0: emb -> featA, rows 0..18
    load_w(0);
    for (int r = rp; r < 19; r += 2) {
        if (!half) {
            float v = mat_half(embg + (size_t)s_ids[r] * 100);
            if (lane < 50) featA[r * 100 + lane] = v;
        } else {
            int chb, S;
            if (r == 0)      { chb = 1;                S = 3; }
            else if (r < 4)  { chb = 4 + (r - 1) * 5;  S = 5; }
            else             { chb = 19 + (r - 4) * 7; S = 7; }
            neigh_row_emb(chb, S, &featA[r * 100]);
        }
    }
    __syncthreads();

    // ---- pass 1: featA (+H3 for L2) -> featB, rows 0..18
    load_w(1);
    for (int r = rp; r < 19; r += 2) {
        if (!half) {
            float v = mat_half(&featA[r * 100]);
            if (lane < 50) featB[r * 100 + lane] = v;
        } else {
            if (r == 0)
                neigh_row(&featA[100], 3, &featB[0]);
            else if (r < 4)
                neigh_row(&featA[(4 + (r - 1) * 5) * 100], 5, &featB[r * 100]);
            else
                neigh_row(H3g + ((size_t)b * 105 + (size_t)(r - 4) * 7) * 100, 7,
                          &featB[r * 100]);
        }
    }
    __syncthreads();

    // ---- pass 2: featB -> featA, rows 0..3
    load_w(2);
    for (int r = rp; r < 4; r += 2) {
        if (!half) {
            float v = mat_half(&featB[r * 100]);
            if (lane < 50) featA[r * 100 + lane] = v;
        } else {
            if (r == 0)
                neigh_row(&featB[100], 3, &featA[0]);
            else
                neigh_row(&featB[(4 + (r - 1) * 5) * 100], 5, &featA[r * 100]);
        }
    }
    __syncthreads();

    // ---- pass 3: featA -> featB row 0
    load_w(3);
    if (rp == 0) {
        if (!half) {
            float v = mat_half(&featA[0]);
            if (lane < 50) featB[lane] = v;
        } else {
            neigh_row(&featA[100], 3, &featB[0]);
        }
    }
    __syncthreads();

    // ---- fc: l2norm(featB[0:100]) @ Wfc[g] + bfc[g] -> spec[b][g][:]
    float2 v2 = *(const float2*)&featB[2 * c];
    float p = (lane < 50) ? (v2.x * v2.x + v2.y * v2.y) : 0.f;
#pragma unroll
    for (int off = 32; off; off >>= 1) p += __shfl_xor(p, off, 64);
    const float inv = 1.f / fmaxf(sqrtf(p), 1e-12f);
    if (wid < 2) {
        const int col = wid * 50 + c;
        const float* Wfb = Wfc + (size_t)g * 10000;
        float acc = 0.f;
#pragma unroll
        for (int d = 0; d < 100; d += 4) {
            float4 xv = *(const float4*)&featB[d];
            acc += xv.x * Wfb[d * 100 + col] + xv.y * Wfb[(d + 1) * 100 + col] +
                   xv.z * Wfb[(d + 2) * 100 + col] + xv.w * Wfb[(d + 3) * 100 + col];
        }
        acc = acc * inv + bfc[g * 100 + col];
        if (lane < 50) spec[((size_t)b * 3 + g) * 100 + col] = acc;
    }
}

// ---------------------------------------------------------------------------
// Fallback monolithic tree kernel (R4, fp32-only) -- used if ws too small.
// ---------------------------------------------------------------------------
DEVFN void mono_row_mm(float* feat, const float* snbw, int xs, const float* ws,
                       const float* wn, float bs, float bn, int lane) {
    float accs = bs, accn = bn;
#pragma unroll
    for (int d = 0; d < 100; d += 4) {
        float4 xv = *(const float4*)&feat[xs * 100 + d];
        float4 nv = *(const float4*)&snbw[d];
        accs += xv.x * ws[d] + xv.y * ws[d + 1] + xv.z * ws[d + 2] + xv.w * ws[d + 3];
        accn += nv.x * wn[d] + nv.y * wn[d + 1] + nv.z * wn[d + 2] + nv.w * wn[d + 3];
    }
    feat[xs * 100 + lane] = fmaxf(accs, 0.f);
    feat[xs * 100 + lane + 50] = fmaxf(accn, 0.f);
}

template <int S>
DEVFN void mono_level(float* feat, float (*snb)[104], int Ok, int Ok1, int R,
                      const float* ws, const float* wn, float bs, float bn,
                      int wid, int lane) {
    for (int j = wid; j < R; j += 4) {
        if (lane < 50) {
            float a0 = 0.f, a1 = 0.f;
#pragma unroll
            for (int s = 0; s < S; ++s) {
                float2 cc = *(const float2*)&feat[(Ok1 + j * S + s) * 100 + 2 * lane];
                a0 += cc.x;
                a1 += cc.y;
            }
            const float inv = 1.f / (float)S;
            *(float2*)&snb[wid][2 * lane] = make_float2(a0 * inv, a1 * inv);
            mono_row_mm(feat, snb[wid], Ok + j, ws, wn, bs, bn, lane);
        }
    }
}

__global__ __launch_bounds__(256, 2) void sage_mono(
    const int* __restrict__ nodeids, const int* __restrict__ n0,
    const int* __restrict__ n1, const int* __restrict__ n2,
    const int* __restrict__ n3, const float* __restrict__ emb,
    const float* __restrict__ Wself, const float* __restrict__ bself,
    const float* __restrict__ Wneigh, const float* __restrict__ bneigh,
    const float* __restrict__ Wfc, const float* __restrict__ bfc,
    float* __restrict__ spec) {
    const int b = blockIdx.x, g = blockIdx.y;
    const int tid = threadIdx.x, wid = tid >> 6, lane = tid & 63;

    __shared__ __align__(16) float feat[12400];
    __shared__ __align__(16) float snb[4][104];
    __shared__ int s_ids[124];
    __shared__ int s_n3[945];
    __shared__ __align__(16) float s_xn[104];
    __shared__ float s_red[256];

    const float* embg = emb + (size_t)g * 10000000;

    if (tid == 0)       s_ids[0]   = nodeids[b];
    else if (tid < 4)   s_ids[tid] = n0[g * 1536  + b * 3   + (tid - 1)];
    else if (tid < 19)  s_ids[tid] = n1[g * 7680  + b * 15  + (tid - 4)];
    else if (tid < 124) s_ids[tid] = n2[g * 53760 + b * 105 + (tid - 19)];
    for (int i = tid; i < 945; i += 256) s_n3[i] = n3[g * 483840 + b * 945 + i];
    __syncthreads();

    for (int row = wid; row < 124; row += 4) {
        if (lane < 50) {
            *(float2*)&feat[row * 100 + 2 * lane] =
                *(const float2*)(embg + (size_t)s_ids[row] * 100 + 2 * lane);
        }
    }
    __syncthreads();

    float ws[100], wn[100];
    for (int l = 0; l < 4; ++l) {
        const float* Wsb = Wself + (size_t)(g * 4 + l) * 5000;
        const float* Wnb = Wneigh + (size_t)(g * 4 + l) * 5000;
        float bs = 0.f, bn = 0.f;
        if (lane < 50) {
            bs = bself[(g * 4 + l) * 50 + lane];
            bn = bneigh[(g * 4 + l) * 50 + lane];
#pragma unroll
            for (int d = 0; d < 100; ++d) {
                ws[d] = Wsb[d * 50 + lane];
                wn[d] = Wnb[d * 50 + lane];
            }
        }
        mono_level<3>(feat, snb, 0, 1, 1, ws, wn, bs, bn, wid, lane);
        __syncthreads();
        if (l <= 2) {
            mono_level<5>(feat, snb, 1, 4, 3, ws, wn, bs, bn, wid, lane);
            __syncthreads();
        }
        if (l <= 1) {
            mono_level<7>(feat, snb, 4, 19, 15, ws, wn, bs, bn, wid, lane);
            __syncthreads();
        }
        if (l == 0) {
            for (int j = wid; j < 105; j += 4) {
                if (lane < 50) {
                    float a0 = 0.f, a1 = 0.f;
#pragma unroll
                    for (int s = 0; s < 9; ++s) {
                        float2 cc = *(const float2*)(
                            embg + (size_t)s_n3[j * 9 + s] * 100 + 2 * lane);
                        a0 += cc.x;
                        a1 += cc.y;
                    }
                    *(float2*)&snb[wid][2 * lane] =
                        make_float2(a0 * (1.f / 9.f), a1 * (1.f / 9.f));
                    mono_row_mm(feat, snb[wid], 19 + j, ws, wn, bs, bn, lane);
                }
            }
            __syncthreads();
        }
    }

    const float v = (tid < 100) ? feat[tid] : 0.f;
    s_red[tid] = v * v;
    __syncthreads();
    for (int s = 128; s > 0; s >>= 1) {
        if (tid < s) s_red[tid] += s_red[tid + s];
        __syncthreads();
    }
    const float inv = 1.f / fmaxf(sqrtf(s_red[0]), 1e-12f);
    if (tid < 100) s_xn[tid] = v * inv;
    __syncthreads();
    if (tid < 100) {
        const float* Wfb = Wfc + (size_t)g * 10000;
        float acc = bfc[g * 100 + tid];
#pragma unroll 4
        for (int d = 0; d < 100; ++d) acc += s_xn[d] * Wfb[d * 100 + tid];
        spec[((size_t)b * 3 + g) * 100 + tid] = acc;
    }
}

// ---------------------------------------------------------------------------
// Kernel C: attention v2.  Block per sample, 4 waves with roles, shuffle
// reductions, 6 barriers.  fp32 output.
// ---------------------------------------------------------------------------
__global__ __launch_bounds__(256) void attn_out(
    const float* __restrict__ spec, const int* __restrict__ nodeids,
    const int* __restrict__ edgetypes, const float* __restrict__ lng,
    const float* __restrict__ lnb, const float* __restrict__ Wq,
    const float* __restrict__ Wk, const float* __restrict__ Wv,
    const float* __restrict__ Wo, const float* __restrict__ refl,
    const float* __restrict__ base, float* __restrict__ out) {
    const int b = blockIdx.x, tid = threadIdx.x;
    const int wid = tid >> 6, lane = tid & 63;
    const int c = min(lane, 49);

    __shared__ __align__(16) float sp[304];
    __shared__ __align__(16) float qn[104];
    __shared__ __align__(16) float sQ[104];
    __shared__ __align__(16) float sK[304];
    __shared__ __align__(16) float sV[304];
    __shared__ __align__(16) float sctx[104];
    __shared__ __align__(16) float so[104];
    __shared__ float ssc[4];
    __shared__ float sred[4];

    for (int u = tid; u < 300; u += 256) sp[u] = spec[(size_t)b * 300 + u];
    const int e = edgetypes[b];
    const int nid = nodeids[b];
    __syncthreads();

    if (wid == 3) {
        // LN of row e + Q projection
        float2 v = *(const float2*)&sp[e * 100 + 2 * c];
        float m = (lane < 50) ? (v.x + v.y) : 0.f;
#pragma unroll
        for (int off = 32; off; off >>= 1) m += __shfl_xor(m, off, 64);
        const float mu = m * 0.01f;
        const float dx = v.x - mu, dy = v.y - mu;
        float vv = (lane < 50) ? (dx * dx + dy * dy) : 0.f;
#pragma unroll
        for (int off = 32; off; off >>= 1) vv += __shfl_xor(vv, off, 64);
        const float rs = rsqrtf(vv * 0.01f + 1e-6f);
        if (lane < 50)
            *(float2*)&qn[2 * lane] =
                make_float2(dx * rs * lng[2 * c] + lnb[2 * c],
                            dy * rs * lng[2 * c + 1] + lnb[2 * c + 1]);
        float q0 = 0.f, q1 = 0.f;
#pragma unroll
        for (int d = 0; d < 100; d += 4) {
            float4 x = *(const float4*)&qn[d];
            q0 += x.x * Wq[d * 100 + c] + x.y * Wq[(d + 1) * 100 + c] +
                  x.z * Wq[(d + 2) * 100 + c] + x.w * Wq[(d + 3) * 100 + c];
            q1 += x.x * Wq[d * 100 + c + 50] + x.y * Wq[(d + 1) * 100 + c + 50] +
                  x.z * Wq[(d + 2) * 100 + c + 50] + x.w * Wq[(d + 3) * 100 + c + 50];
        }
        if (lane < 50) { sQ[c] = q0; sQ[c + 50] = q1; }
    } else {
        const int h = wid;
        float k0 = 0.f, k1 = 0.f, v0 = 0.f, v1 = 0.f;
#pragma unroll
        for (int d = 0; d < 100; d += 4) {
            float4 x = *(const float4*)&sp[h * 100 + d];
            k0 += x.x * Wk[d * 100 + c] + x.y * Wk[(d + 1) * 100 + c] +
                  x.z * Wk[(d + 2) * 100 + c] + x.w * Wk[(d + 3) * 100 + c];
            k1 += x.x * Wk[d * 100 + c + 50] + x.y * Wk[(d + 1) * 100 + c + 50] +
                  x.z * Wk[(d + 2) * 100 + c + 50] + x.w * Wk[(d + 3) * 100 + c + 50];
            v0 += x.x * Wv[d * 100 + c] + x.y * Wv[(d + 1) * 100 + c] +
                  x.z * Wv[(d + 2) * 100 + c] + x.w * Wv[(d + 3) * 100 + c];
            v1 += x.x * Wv[d * 100 + c + 50] + x.y * Wv[(d + 1) * 100 + c + 50] +
                  x.z * Wv[(d + 2) * 100 + c + 50] + x.w * Wv[(d + 3) * 100 + c + 50];
        }
        if (lane < 50) {
            sK[h * 100 + c] = k0;
            sK[h * 100 + c + 50] = k1;
            sV[h * 100 + c] = v0;
            sV[h * 100 + c + 50] = v1;
        }
    }
    __syncthreads();

    if (wid < 3) {
        float2 q = *(const float2*)&sQ[2 * c];
        float2 k = *(const float2*)&sK[wid * 100 + 2 * c];
        float p = (lane < 50) ? (q.x * k.x + q.y * k.y) : 0.f;
#pragma unroll
        for (int off = 32; off; off >>= 1) p += __shfl_xor(p, off, 64);
        if (lane == 0) ssc[wid] = p * 0.1f;  // 1/sqrt(100)
    }
    __syncthreads();

    const float s0 = ssc[0], s1 = ssc[1], s2 = ssc[2];
    const float mm = fmaxf(s0, fmaxf(s1, s2));
    const float e0 = expf(s0 - mm), e1 = expf(s1 - mm), e2 = expf(s2 - mm);
    const float wsum = 1.f / (e0 + e1 + e2);

    if (wid == 0 && lane < 50) {
        float2 a = *(const float2*)&sV[2 * c];
        float2 bb = *(const float2*)&sV[100 + 2 * c];
        float2 cc = *(const float2*)&sV[200 + 2 * c];
        *(float2*)&sctx[2 * lane] =
            make_float2((e0 * a.x + e1 * bb.x + e2 * cc.x) * wsum,
                        (e0 * a.y + e1 * bb.y + e2 * cc.y) * wsum);
    }
    __syncthreads();

    if (wid < 2) {
        const int col = wid * 50 + c;
        float acc = sp[e * 100 + col];  // residual
#pragma unroll
        for (int d = 0; d < 100; d += 4) {
            float4 x = *(const float4*)&sctx[d];
            acc += x.x * Wo[d * 100 + col] + x.y * Wo[(d + 1) * 100 + col] +
                   x.z * Wo[(d + 2) * 100 + col] + x.w * Wo[(d + 3) * 100 + col];
        }
        if (lane < 50) so[col] = acc;
    }
    __syncthreads();

    const int col2 = wid * 50 + c;  // 0..199 over 4 waves
    float acc = base[(size_t)nid * 200 + col2];
#pragma unroll
    for (int d = 0; d < 100; d += 4) {
        float4 x = *(const float4*)&so[d];
        acc += x.x * refl[(size_t)(e * 100 + d) * 200 + col2] +
               x.y * refl[(size_t)(e * 100 + d + 1) * 200 + col2] +
               x.z * refl[(size_t)(e * 100 + d + 2) * 200 + col2] +
               x.w * refl[(size_t)(e * 100 + d + 3) * 200 + col2];
    }
    float sq = (lane < 50) ? acc * acc : 0.f;
#pragma unroll
    for (int off = 32; off; off >>= 1) sq += __shfl_xor(sq, off, 64);
    if (lane == 0) sred[wid] = sq;
    __syncthreads();
    const float ss = sred[0] + sred[1] + sred[2] + sred[3];
    const float inv = 1.f / fmaxf(sqrtf(ss), 1e-12f);
    if (lane < 50) out[(size_t)b * 200 + col2] = acc * inv;
}

// ---------------------------------------------------------------------------
extern "C" void kernel_launch(void* const* d_in, const int* in_sizes, int n_in,
                              void* d_out, int out_size, void* d_ws,
                              size_t ws_size, hipStream_t stream) {
    (void)in_sizes; (void)n_in; (void)out_size;
    const int* nodeids   = (const int*)d_in[0];
    const int* edgetypes = (const int*)d_in[1];
    const int* n0 = (const int*)d_in[2];
    const int* n1 = (const int*)d_in[3];
    const int* n2 = (const int*)d_in[4];
    const int* n3 = (const int*)d_in[5];
    const float* base   = (const float*)d_in[6];
    const float* emb    = (const float*)d_in[7];
    const float* Wself  = (const float*)d_in[8];
    const float* bself  = (const float*)d_in[9];
    const float* Wneigh = (const float*)d_in[10];
    const float* bneigh = (const float*)d_in[11];
    const float* Wfc    = (const float*)d_in[12];
    const float* bfc    = (const float*)d_in[13];
    const float* lng    = (const float*)d_in[14];
    const float* lnb    = (const float*)d_in[15];
    const float* Wq     = (const float*)d_in[16];
    const float* Wk     = (const float*)d_in[17];
    const float* Wv     = (const float*)d_in[18];
    const float* Wo     = (const float*)d_in[19];
    const float* refl   = (const float*)d_in[20];
    float* out = (float*)d_out;

    float* SPEC = (float*)d_ws;                              // 614,400 x4 B
    float* H3   = (float*)((char*)d_ws + 4 * 1024 * 1024);   // 3*53760*100 f32
    const size_t need = 4ull * 1024 * 1024 + 64512000ull;

    if (ws_size >= need) {
        pass0_l3<<<dim3(336, 3), 256, 0, stream>>>(n2, n3, emb, Wself, bself,
                                                   Wneigh, bneigh, H3);
        sage_tree<<<dim3(512, 3), 256, 0, stream>>>(nodeids, n0, n1, n2, emb,
                                                    Wself, bself, Wneigh, bneigh,
                                                    Wfc, bfc, H3, SPEC);
    } else {
        sage_mono<<<dim3(512, 3), 256, 0, stream>>>(nodeids, n0, n1, n2, n3, emb,
                                                    Wself, bself, Wneigh, bneigh,
                                                    Wfc, bfc, SPEC);
    }
    attn_out<<<dim3(512), 256, 0, stream>>>(SPEC, nodeids, edgetypes, lng, lnb,
                                            Wq, Wk, Wv, Wo, refl, base, out);
}